// Round 7
// baseline (146.154 us; speedup 1.0000x reference)
//
#include <hip/hip_runtime.h>
#include <math.h>

#define NBATCH 4
#define NPTS   8192
#define KNN    8
#define NCH    4096
#define SLICES 16
#define SLEN   (NPTS / SLICES)   // 512 candidates per slice-wave

// ws layout: [0..40) bytes: 5 double accumulators
//            [256, 256+NBATCH*NPTS*16): float4 (x,y,z,|p|^2) per point
#define PTS4_OFF 256

// single-block insert: 8 instrs, bd pinned via tied "+v", in-place descending
// order reads only pre-block values => depth-1 sorted insert (ascending top-8).
#define INSERT8(bd, key)                                          \
    asm("v_med3_u32 %7, %8, %6, %7\n\t"                           \
        "v_med3_u32 %6, %8, %5, %6\n\t"                           \
        "v_med3_u32 %5, %8, %4, %5\n\t"                           \
        "v_med3_u32 %4, %8, %3, %4\n\t"                           \
        "v_med3_u32 %3, %8, %2, %3\n\t"                           \
        "v_med3_u32 %2, %8, %1, %2\n\t"                           \
        "v_med3_u32 %1, %8, %0, %1\n\t"                           \
        "v_min_u32  %0, %0, %8"                                   \
        : "+v"(bd[0]), "+v"(bd[1]), "+v"(bd[2]), "+v"(bd[3]),     \
          "+v"(bd[4]), "+v"(bd[5]), "+v"(bd[6]), "+v"(bd[7])      \
        : "v"(key))

// points -> float4(x,y,z,|p|^2)
__global__ __launch_bounds__(256) void prep_kernel(const float* __restrict__ pts,
                                                   float4* __restrict__ pts4) {
    const int i = blockIdx.x * 256 + threadIdx.x;   // 0..32767
    const float x = pts[i * 3 + 0];
    const float y = pts[i * 3 + 1];
    const float z = pts[i * 3 + 2];
    pts4[i] = make_float4(x, y, z, x * x + y * y + z * z);
}

// Fused MSE: blocks [0,96) -> recon (float4, 24576 exactly); [96,112) -> percep.
__global__ __launch_bounds__(256) void mse_kernel(const float* __restrict__ a,
                                                  const float* __restrict__ b,
                                                  const float* __restrict__ a2,
                                                  const float* __restrict__ b2,
                                                  double* __restrict__ acc) {
    const int t = threadIdx.x;
    const int blk = blockIdx.x;
    float s;
    int which;
    if (blk < 96) {
        which = 0;
        const int i = blk * 256 + t;
        const float4 va = reinterpret_cast<const float4*>(a)[i];
        const float4 vb = reinterpret_cast<const float4*>(b)[i];
        const float dx = va.x - vb.x, dy = va.y - vb.y;
        const float dz = va.z - vb.z, dw = va.w - vb.w;
        s = dx * dx + dy * dy + dz * dz + dw * dw;
    } else {
        which = 1;
        const int i = (blk - 96) * 256 + t;
        const float d = a2[i] - b2[i];
        s = d * d;
    }
#pragma unroll
    for (int o = 32; o > 0; o >>= 1) s += __shfl_down(s, o, 64);
    __shared__ float wsum[4];
    if ((t & 63) == 0) wsum[t >> 6] = s;
    __syncthreads();
    if (t == 0)
        atomicAdd(&acc[which], (double)(wsum[0] + wsum[1] + wsum[2] + wsum[3]));
}

// Continuity kNN, scalar-broadcast form: block = 16 waves x 1024 thr; every wave
// holds the SAME 64 queries (one per lane) and scans its own 512-candidate slice
// via wave-uniform s_load_dwordx4 of float4(x,y,z,|p|^2). Hot loop: 14 VALU/cand
// (1 add + 3 fma + and + or + 8 med3), zero LDS/VMEM. Key = monotone distance
// surrogate |p|^2-2p.q+|q|^2+eps bits | index; self filtered at merge.
__global__ __launch_bounds__(1024, 8) void cont_kernel(const float4* __restrict__ pts4,
                                                       double* __restrict__ acc) {
    __shared__ unsigned mrg[SLICES][KNN][64];   // 32 KB, lane-consecutive
    const int t    = threadIdx.x;
    const int lane = t & 63;
    const int w    = __builtin_amdgcn_readfirstlane(t >> 6);   // slice id (SGPR)
    const int nqw  = NPTS / 64;                 // 128 query-waves per batch
    const int b    = blockIdx.x / nqw;
    const int q0   = (blockIdx.x % nqw) * 64;
    const float4* __restrict__ P4 = pts4 + (size_t)b * NPTS;

    const float4 qv = P4[q0 + lane];
    const float m2x = -2.f * qv.x, m2y = -2.f * qv.y, m2z = -2.f * qv.z;
    const float qnp = qv.w + 1e-6f;             // keeps self-key positive-ish

    unsigned bd[KNN];
#pragma unroll
    for (int s = 0; s < KNN; ++s) bd[s] = 0xFFFFFFFFu;

    const float4* __restrict__ S = P4 + w * SLEN;   // uniform base
    const unsigned jb = (unsigned)(w * SLEN);

#pragma unroll 8
    for (int j = 0; j < SLEN; ++j) {
        const float4 c = S[j];                      // wave-uniform scalar load
        float s1 = fmaf(c.z, m2z, c.w + qnp);
        s1 = fmaf(c.y, m2y, s1);
        s1 = fmaf(c.x, m2x, s1);
        const unsigned key =
            (__float_as_uint(s1) & 0xFFFFE000u) | (jb + (unsigned)j);
        INSERT8(bd, key);                           // self filtered at merge
    }

#pragma unroll
    for (int s = 0; s < KNN; ++s) mrg[w][s][lane] = bd[s];
    __syncthreads();

    if (w == 0) {   // wave 0 merges all 16 slices; one query per lane
        const unsigned selfidx = (unsigned)(q0 + lane);
        unsigned best[KNN];
#pragma unroll
        for (int s = 0; s < KNN; ++s) best[s] = 0xFFFFFFFFu;
        for (int sl = 0; sl < SLICES; ++sl) {
#pragma unroll
            for (int u = 0; u < KNN; ++u) {
                unsigned key = mrg[sl][u][lane];
                key = ((key & 0x1FFFu) == selfidx) ? 0xFFFFFFFFu : key;  // drop self
                INSERT8(best, key);
            }
        }
        // sum of squared deviations from centroid: sum|p|^2 - |sum p|^2 / 8
        float sx = 0.f, sy = 0.f, sz = 0.f, sw = 0.f;
#pragma unroll
        for (int s = 0; s < KNN; ++s) {
            const float4 n = P4[best[s] & 0x1FFFu];
            sx += n.x; sy += n.y; sz += n.z; sw += n.w;
        }
        float ssum = sw - (sx * sx + sy * sy + sz * sz) * (1.f / KNN);
#pragma unroll
        for (int o = 32; o > 0; o >>= 1) ssum += __shfl_down(ssum, o, 64);
        if (lane == 0) atomicAdd(&acc[2], (double)ssum);
    }
}

// Boundary: grid 256 x 256 thr; 16 queries x 16 segs of 256 j's per block.
// chunk2 staged as float4 (x,y,z,|p|^2); min over (|p|^2 - 2p.q), |q|^2 added once.
// Per-seg rotated start (+2*(seg&3)) de-conflicts the 4 seg-groups' LDS reads.
__global__ __launch_bounds__(256) void bnd_kernel(const float* __restrict__ c1,
                                                  const float* __restrict__ c2,
                                                  double* __restrict__ acc) {
    __shared__ float4 p2[NCH];          // 64 KB
    __shared__ float qn_s[16];
    __shared__ float pmin[16][17];
    __shared__ float bsum[16], bcnt[16];
    const int t = threadIdx.x;
#pragma unroll
    for (int r = 0; r < 16; ++r) {
        const int idx = t + 256 * r;
        const float x = c2[idx * 3 + 0];
        const float y = c2[idx * 3 + 1];
        const float z = c2[idx * 3 + 2];
        p2[idx] = make_float4(x, y, z, x * x + y * y + z * z);
    }
    const int q   = t & 15;
    const int seg = t >> 4;
    const int qi  = blockIdx.x * 16 + q;
    const float qx = c1[qi * 3 + 0];
    const float qy = c1[qi * 3 + 1];
    const float qz = c1[qi * 3 + 2];
    const float m2x = -2.f * qx, m2y = -2.f * qy, m2z = -2.f * qz;
    if (seg == 0) qn_s[q] = qx * qx + qy * qy + qz * qz;
    __syncthreads();

    float m = 3.0e38f;
    const int j0  = seg * (NCH / 16);
    const int rot = (seg & 3) * 2;
#pragma unroll 8
    for (int jj = 0; jj < NCH / 16; ++jj) {
        const float4 c = p2[j0 + ((jj + rot) & (NCH / 16 - 1))];
        float s1 = fmaf(c.x, m2x, c.w);
        s1 = fmaf(c.y, m2y, s1);
        s1 = fmaf(c.z, m2z, s1);
        m = fminf(m, s1);
    }
    pmin[q][seg] = m;
    __syncthreads();
    if (t < 16) {
        float mm = pmin[t][0];
#pragma unroll
        for (int s = 1; s < 16; ++s) mm = fminf(mm, pmin[t][s]);
        const float d = sqrtf(fmaxf(mm + qn_s[t], 0.f));
        const bool in = d < 0.1f;
        bsum[t] = in ? d   : 0.f;
        bcnt[t] = in ? 1.f : 0.f;
    }
    __syncthreads();
    if (t == 0) {
        double sc = 0.0, sn = 0.0;
        for (int i = 0; i < 16; ++i) { sc += (double)bsum[i]; sn += (double)bcnt[i]; }
        atomicAdd(&acc[3], sc);
        atomicAdd(&acc[4], sn);
    }
}

__global__ void fin_kernel(const double* __restrict__ acc, float* __restrict__ out) {
    if (threadIdx.x == 0) {
        const double recon  = acc[0] / (double)(NBATCH * NPTS * 3);
        const double percep = acc[1] / 4096.0;
        const double cont   = acc[2] / (double)(NBATCH * NPTS * KNN);
        const double cnt    = acc[4];
        const double bnd    = (cnt > 0.0) ? acc[3] / ((cnt > 1.0) ? cnt : 1.0) : 0.0;
        const double total  = 1.0 * recon + 0.5 * percep + 0.5 * cont + 1.0 * bnd;
        out[0] = (float)recon;
        out[1] = (float)percep;
        out[2] = (float)cont;
        out[3] = (float)bnd;
        out[4] = (float)total;
    }
}

extern "C" void kernel_launch(void* const* d_in, const int* in_sizes, int n_in,
                              void* d_out, int out_size, void* d_ws, size_t ws_size,
                              hipStream_t stream) {
    const float* pred = (const float*)d_in[0];
    const float* targ = (const float*)d_in[1];
    const float* pf   = (const float*)d_in[2];
    const float* tf   = (const float*)d_in[3];
    const float* c1   = (const float*)d_in[4];
    const float* c2   = (const float*)d_in[5];
    float* out  = (float*)d_out;
    double* acc = (double*)d_ws;
    float4* pts4 = (float4*)((char*)d_ws + PTS4_OFF);

    hipMemsetAsync(acc, 0, 5 * sizeof(double), stream);
    hipLaunchKernelGGL(prep_kernel, dim3(NBATCH * NPTS / 256), dim3(256), 0, stream,
                       pred, pts4);
    hipLaunchKernelGGL(cont_kernel, dim3(NBATCH * (NPTS / 64)), dim3(1024), 0, stream,
                       pts4, acc);
    hipLaunchKernelGGL(mse_kernel, dim3(112), dim3(256), 0, stream,
                       pred, targ, pf, tf, acc);
    hipLaunchKernelGGL(bnd_kernel, dim3(NCH / 16), dim3(256), 0, stream, c1, c2, acc);
    hipLaunchKernelGGL(fin_kernel, dim3(1), dim3(64), 0, stream, acc, out);
}

// Round 8
// 122.235 us; speedup vs baseline: 1.1957x; 1.1957x over previous
//
#include <hip/hip_runtime.h>
#include <math.h>

#define NBATCH 4
#define NPTS   8192
#define KNN    8
#define NCH    4096
#define SLICES 16
#define SLEN   (NPTS / SLICES)   // 512 candidates per slice-wave
#define PAIRS  (SLEN / 2)        // 256 packed pairs per slice
#define PB_OFF 256               // pair-buffer offset in d_ws (bytes)

typedef float v2f __attribute__((ext_vector_type(2)));

// ws layout: [0..40): 5 double accumulators
//            [PB_OFF, PB_OFF + NBATCH*NPTS*16): pair-interleaved point data,
//            8 floats per point-PAIR: {x0,x1,y0,y1,z0,z1,|p0|^2,|p1|^2}

// single-block insert: 8 instrs, bd pinned via tied "+v", in-place descending
// order reads only pre-block values => depth-1 sorted insert (ascending top-8).
#define INSERT8(bd, key)                                          \
    asm("v_med3_u32 %7, %8, %6, %7\n\t"                           \
        "v_med3_u32 %6, %8, %5, %6\n\t"                           \
        "v_med3_u32 %5, %8, %4, %5\n\t"                           \
        "v_med3_u32 %4, %8, %3, %4\n\t"                           \
        "v_med3_u32 %3, %8, %2, %3\n\t"                           \
        "v_med3_u32 %2, %8, %1, %2\n\t"                           \
        "v_med3_u32 %1, %8, %0, %1\n\t"                           \
        "v_min_u32  %0, %0, %8"                                   \
        : "+v"(bd[0]), "+v"(bd[1]), "+v"(bd[2]), "+v"(bd[3]),     \
          "+v"(bd[4]), "+v"(bd[5]), "+v"(bd[6]), "+v"(bd[7])      \
        : "v"(key))

// points (float3) -> pair-interleaved {x0,x1,y0,y1,z0,z1,w0,w1}
__global__ __launch_bounds__(256) void prep_kernel(const float* __restrict__ pts,
                                                   float* __restrict__ pb) {
    const int i = blockIdx.x * 256 + threadIdx.x;   // pair index 0..16383
    const float2 u0 = *reinterpret_cast<const float2*>(pts + (size_t)i * 6 + 0); // x0 y0
    const float2 u1 = *reinterpret_cast<const float2*>(pts + (size_t)i * 6 + 2); // z0 x1
    const float2 u2 = *reinterpret_cast<const float2*>(pts + (size_t)i * 6 + 4); // y1 z1
    const float x0 = u0.x, y0 = u0.y, z0 = u1.x;
    const float x1 = u1.y, y1 = u2.x, z1 = u2.y;
    float4* o = reinterpret_cast<float4*>(pb + (size_t)i * 8);
    o[0] = make_float4(x0, x1, y0, y1);
    o[1] = make_float4(z0, z1,
                       x0 * x0 + y0 * y0 + z0 * z0,
                       x1 * x1 + y1 * y1 + z1 * z1);
}

// Continuity kNN, scalar-broadcast + packed-fp32: block = 16 waves; every wave
// holds the SAME 64 queries (one per lane) and scans its own 512-candidate
// slice as 256 pairs via wave-uniform s_loads. Per pair: 1 pk_add + 3 pk_fma
// (dual-fp32 distance surrogate |p|^2-2p.q+|q|^2+eps) + 2 v_and_or key packs
// + 2 branchless med3 top-8 inserts. Self filtered at merge (key idx == qi).
__global__ __launch_bounds__(1024, 8) void cont_kernel(const float* __restrict__ pb,
                                                       double* __restrict__ acc) {
    __shared__ unsigned mrg[SLICES][KNN][64];   // 32 KB, lane-consecutive
    const int t    = threadIdx.x;
    const int lane = t & 63;
    const int w    = __builtin_amdgcn_readfirstlane(t >> 6);   // slice id (SGPR)
    const int nqw  = NPTS / 64;                 // 128 query-waves per batch
    const int b    = blockIdx.x / nqw;
    const int q0   = (blockIdx.x % nqw) * 64;
    const float* __restrict__ B = pb + (size_t)b * NPTS * 4;   // 4 floats/point

    // per-lane query from pair buffer
    const int qi = q0 + lane;
    const float* qp = B + (size_t)(qi >> 1) * 8;
    const int e = qi & 1;
    const float qx = qp[0 + e], qy = qp[2 + e], qz = qp[4 + e], qw = qp[6 + e];
    const float m2x = -2.f * qx, m2y = -2.f * qy, m2z = -2.f * qz;
    const float qnp = qw + 1e-6f;               // keeps key positive
    const v2f qnp2 = {qnp, qnp};
    const v2f m2x2 = {m2x, m2x}, m2y2 = {m2y, m2y}, m2z2 = {m2z, m2z};
    unsigned vmask;
    asm("v_mov_b32 %0, 0xFFFFE000" : "=v"(vmask));

    unsigned bd[KNN];
#pragma unroll
    for (int s = 0; s < KNN; ++s) bd[s] = 0xFFFFFFFFu;

    const float* __restrict__ Sp = B + (size_t)w * PAIRS * 8;  // uniform base
    const unsigned jb = (unsigned)(w * SLEN);

#pragma unroll 4
    for (int j = 0; j < PAIRS; ++j) {
        const float4 ab = *reinterpret_cast<const float4*>(Sp + j * 8);      // x0 x1 y0 y1
        const float4 cd = *reinterpret_cast<const float4*>(Sp + j * 8 + 4);  // z0 z1 w0 w1
        const v2f xp = {ab.x, ab.y}, yp = {ab.z, ab.w};
        const v2f zp = {cd.x, cd.y}, wp = {cd.z, cd.w};
        v2f s2;
        asm("v_pk_add_f32 %0, %1, %2" : "=v"(s2) : "s"(wp), "v"(qnp2));
        asm("v_pk_fma_f32 %0, %1, %2, %0" : "+v"(s2) : "s"(zp), "v"(m2z2));
        asm("v_pk_fma_f32 %0, %1, %2, %0" : "+v"(s2) : "s"(yp), "v"(m2y2));
        asm("v_pk_fma_f32 %0, %1, %2, %0" : "+v"(s2) : "s"(xp), "v"(m2x2));
        const unsigned j0 = jb + 2 * (unsigned)j;
        const unsigned j1 = j0 + 1;
        unsigned k0, k1;
        asm("v_and_or_b32 %0, %1, %2, %3"
            : "=v"(k0) : "v"(__float_as_uint(s2.x)), "v"(vmask), "s"(j0));
        asm("v_and_or_b32 %0, %1, %2, %3"
            : "=v"(k1) : "v"(__float_as_uint(s2.y)), "v"(vmask), "s"(j1));
        INSERT8(bd, k0);
        INSERT8(bd, k1);
    }

#pragma unroll
    for (int s = 0; s < KNN; ++s) mrg[w][s][lane] = bd[s];
    __syncthreads();

    // stage 1: waves 0..3 each merge 4 slices (self filtered here)
    if (w < 4) {
        const unsigned selfidx = (unsigned)qi;
        unsigned best[KNN];
#pragma unroll
        for (int s = 0; s < KNN; ++s) best[s] = 0xFFFFFFFFu;
        for (int sl = 4 * w; sl < 4 * w + 4; ++sl) {
#pragma unroll
            for (int u = 0; u < KNN; ++u) {
                unsigned key = mrg[sl][u][lane];
                key = ((key & 0x1FFFu) == selfidx) ? 0xFFFFFFFFu : key;
                INSERT8(best, key);
            }
        }
#pragma unroll
        for (int s = 0; s < KNN; ++s) mrg[4 * w][s][lane] = best[s];
    }
    __syncthreads();

    // stage 2: wave 0 merges the 4 partials; closed-form deviation sum
    if (w == 0) {
        unsigned best[KNN];
#pragma unroll
        for (int s = 0; s < KNN; ++s) best[s] = 0xFFFFFFFFu;
        for (int g = 0; g < 4; ++g) {
#pragma unroll
            for (int u = 0; u < KNN; ++u) {
                const unsigned key = mrg[4 * g][u][lane];
                INSERT8(best, key);
            }
        }
        float sx = 0.f, sy = 0.f, sz = 0.f, sw = 0.f;
#pragma unroll
        for (int s = 0; s < KNN; ++s) {
            const unsigned n = best[s] & 0x1FFFu;
            const float* np = B + (size_t)(n >> 1) * 8;
            const int e2 = n & 1;
            sx += np[0 + e2]; sy += np[2 + e2]; sz += np[4 + e2]; sw += np[6 + e2];
        }
        float ssum = sw - (sx * sx + sy * sy + sz * sz) * (1.f / KNN);
#pragma unroll
        for (int o = 32; o > 0; o >>= 1) ssum += __shfl_down(ssum, o, 64);
        if (lane == 0) atomicAdd(&acc[2], (double)ssum);
    }
}

// Fused aux: blocks [0,48) recon MSE (float4), [48,56) percep MSE,
// [56,120) boundary (64 queries/block, 8 slice-waves x 512 candidates,
// scalar-broadcast loads of chunk2, plain fmin merge).
__global__ __launch_bounds__(512) void aux_kernel(const float* __restrict__ a,
                                                  const float* __restrict__ bt,
                                                  const float* __restrict__ a2,
                                                  const float* __restrict__ b2,
                                                  const float* __restrict__ c1,
                                                  const float* __restrict__ c2,
                                                  double* __restrict__ acc) {
    __shared__ float red[8];
    __shared__ float mn[8][64];
    const int t = threadIdx.x;
    const int blk = blockIdx.x;
    if (blk < 56) {
        float s;
        int which;
        if (blk < 48) {
            which = 0;
            const int i = blk * 512 + t;
            const float4 va = reinterpret_cast<const float4*>(a)[i];
            const float4 vb = reinterpret_cast<const float4*>(bt)[i];
            const float dx = va.x - vb.x, dy = va.y - vb.y;
            const float dz = va.z - vb.z, dw = va.w - vb.w;
            s = dx * dx + dy * dy + dz * dz + dw * dw;
        } else {
            which = 1;
            const int i = (blk - 48) * 512 + t;
            const float d = a2[i] - b2[i];
            s = d * d;
        }
#pragma unroll
        for (int o = 32; o > 0; o >>= 1) s += __shfl_down(s, o, 64);
        if ((t & 63) == 0) red[t >> 6] = s;
        __syncthreads();
        if (t == 0) {
            float bs = 0.f;
#pragma unroll
            for (int i = 0; i < 8; ++i) bs += red[i];
            atomicAdd(&acc[which], (double)bs);
        }
    } else {
        const int lane = t & 63;
        const int w = __builtin_amdgcn_readfirstlane(t >> 6);   // 0..7
        const int qi = (blk - 56) * 64 + lane;
        const float qx = c1[qi * 3 + 0];
        const float qy = c1[qi * 3 + 1];
        const float qz = c1[qi * 3 + 2];
        float m = 3.0e38f;
        const float* __restrict__ S = c2 + w * 512 * 3;   // uniform base
#define BCAND(CX, CY, CZ)                                             \
        do {                                                          \
            const float dx = (CX) - qx, dy = (CY) - qy, dz = (CZ) - qz; \
            m = fminf(m, fmaf(dx, dx, fmaf(dy, dy, dz * dz)));        \
        } while (0)
#pragma unroll 4
        for (int j4 = 0; j4 < 512; j4 += 4) {
            const float4 u0 = *reinterpret_cast<const float4*>(S + j4 * 3 + 0);
            const float4 u1 = *reinterpret_cast<const float4*>(S + j4 * 3 + 4);
            const float4 u2 = *reinterpret_cast<const float4*>(S + j4 * 3 + 8);
            BCAND(u0.x, u0.y, u0.z);
            BCAND(u0.w, u1.x, u1.y);
            BCAND(u1.z, u1.w, u2.x);
            BCAND(u2.y, u2.z, u2.w);
        }
#undef BCAND
        mn[w][lane] = m;
        __syncthreads();
        if (w == 0) {
            float mm = mn[0][lane];
#pragma unroll
            for (int s = 1; s < 8; ++s) mm = fminf(mm, mn[s][lane]);
            const float d = sqrtf(mm);
            const bool in = d < 0.1f;
            float sc = in ? d : 0.f;
            float sn = in ? 1.f : 0.f;
#pragma unroll
            for (int o = 32; o > 0; o >>= 1) {
                sc += __shfl_down(sc, o, 64);
                sn += __shfl_down(sn, o, 64);
            }
            if (lane == 0) {
                atomicAdd(&acc[3], (double)sc);
                atomicAdd(&acc[4], (double)sn);
            }
        }
    }
}

__global__ void fin_kernel(const double* __restrict__ acc, float* __restrict__ out) {
    if (threadIdx.x == 0) {
        const double recon  = acc[0] / (double)(NBATCH * NPTS * 3);
        const double percep = acc[1] / 4096.0;
        const double cont   = acc[2] / (double)(NBATCH * NPTS * KNN);
        const double cnt    = acc[4];
        const double bnd    = (cnt > 0.0) ? acc[3] / ((cnt > 1.0) ? cnt : 1.0) : 0.0;
        const double total  = 1.0 * recon + 0.5 * percep + 0.5 * cont + 1.0 * bnd;
        out[0] = (float)recon;
        out[1] = (float)percep;
        out[2] = (float)cont;
        out[3] = (float)bnd;
        out[4] = (float)total;
    }
}

extern "C" void kernel_launch(void* const* d_in, const int* in_sizes, int n_in,
                              void* d_out, int out_size, void* d_ws, size_t ws_size,
                              hipStream_t stream) {
    const float* pred = (const float*)d_in[0];
    const float* targ = (const float*)d_in[1];
    const float* pf   = (const float*)d_in[2];
    const float* tf   = (const float*)d_in[3];
    const float* c1   = (const float*)d_in[4];
    const float* c2   = (const float*)d_in[5];
    float* out  = (float*)d_out;
    double* acc = (double*)d_ws;
    float* pb   = (float*)((char*)d_ws + PB_OFF);

    hipMemsetAsync(acc, 0, 5 * sizeof(double), stream);
    hipLaunchKernelGGL(prep_kernel, dim3(NBATCH * NPTS / 2 / 256), dim3(256), 0, stream,
                       pred, pb);
    hipLaunchKernelGGL(cont_kernel, dim3(NBATCH * (NPTS / 64)), dim3(1024), 0, stream,
                       pb, acc);
    hipLaunchKernelGGL(aux_kernel, dim3(120), dim3(512), 0, stream,
                       pred, targ, pf, tf, c1, c2, acc);
    hipLaunchKernelGGL(fin_kernel, dim3(1), dim3(64), 0, stream, acc, out);
}

// Round 9
// 78.350 us; speedup vs baseline: 1.8654x; 1.5601x over previous
//
#include <hip/hip_runtime.h>
#include <math.h>

#define NBATCH 4
#define NPTS   8192
#define KNN    8
#define NCH    4096
#define SLICES 16
#define SLEN   512               // candidates per slice-wave
#define NWIN   8                 // windows per slice
#define WLEN   64                // candidates per window
#define PB_OFF 256
#define C2_OFF (PB_OFF + NBATCH * NPTS * 16)   // after 512KB pair buffer

typedef float v2f __attribute__((ext_vector_type(2)));

__device__ __forceinline__ unsigned umin32(unsigned a, unsigned b) { return a < b ? a : b; }

// single-block insert: 8 instrs, bd pinned via tied "+v", in-place descending
// order reads only pre-block values => depth-1 sorted insert (ascending top-8).
#define INSERT8(bd, key)                                          \
    asm("v_med3_u32 %7, %8, %6, %7\n\t"                           \
        "v_med3_u32 %6, %8, %5, %6\n\t"                           \
        "v_med3_u32 %5, %8, %4, %5\n\t"                           \
        "v_med3_u32 %4, %8, %3, %4\n\t"                           \
        "v_med3_u32 %3, %8, %2, %3\n\t"                           \
        "v_med3_u32 %2, %8, %1, %2\n\t"                           \
        "v_med3_u32 %1, %8, %0, %1\n\t"                           \
        "v_min_u32  %0, %0, %8"                                   \
        : "+v"(bd[0]), "+v"(bd[1]), "+v"(bd[2]), "+v"(bd[3]),     \
          "+v"(bd[4]), "+v"(bd[5]), "+v"(bd[6]), "+v"(bd[7])      \
        : "v"(key))

// points (float3) -> pair-interleaved {x0,x1,y0,y1,z0,z1,|p0|^2,|p1|^2};
// tasks [0,16384) = pred pairs, [16384,18432) = chunk2 pairs; also zeroes acc.
__global__ __launch_bounds__(256) void prep_kernel(const float* __restrict__ pts,
                                                   const float* __restrict__ c2,
                                                   float* __restrict__ pb,
                                                   float* __restrict__ c2p,
                                                   double* __restrict__ acc) {
    const int gi = blockIdx.x * 256 + threadIdx.x;
    if (gi < 8) acc[gi] = 0.0;
    const float* src;
    float* dst;
    int pi;
    if (gi < NBATCH * NPTS / 2) { src = pts; dst = pb; pi = gi; }
    else { src = c2; dst = c2p; pi = gi - NBATCH * NPTS / 2; }
    const float2 u0 = *reinterpret_cast<const float2*>(src + (size_t)pi * 6 + 0);
    const float2 u1 = *reinterpret_cast<const float2*>(src + (size_t)pi * 6 + 2);
    const float2 u2 = *reinterpret_cast<const float2*>(src + (size_t)pi * 6 + 4);
    const float x0 = u0.x, y0 = u0.y, z0 = u1.x;
    const float x1 = u1.y, y1 = u2.x, z1 = u2.y;
    float4* o = reinterpret_cast<float4*>(dst + (size_t)pi * 8);
    o[0] = make_float4(x0, x1, y0, y1);
    o[1] = make_float4(z0, z1, x0 * x0 + y0 * y0 + z0 * z0,
                               x1 * x1 + y1 * y1 + z1 * z1);
}

// Continuity kNN, window-min form: block = 16 slice-waves; every wave holds the
// SAME 64 queries (one per lane), scans its 512-candidate slice as 8 windows of
// 64, keeping only each window's min key (26-bit d2 surrogate | 6-bit local idx,
// idx as inline-const via full unroll). Per pair: 4 pk + 2 and_or + 2 min.
// Window minima re-packed to 19-bit d2 | 13-bit global idx, then exact top-8
// merge over the 128 window minima (med3 INSERT8, self filtered by index).
__global__ __launch_bounds__(1024, 8) void cont_kernel(const float* __restrict__ pb,
                                                       double* __restrict__ acc) {
    __shared__ unsigned mrg[SLICES][KNN][64];   // 32 KB, lane-consecutive
    const int t    = threadIdx.x;
    const int lane = t & 63;
    const int w    = __builtin_amdgcn_readfirstlane(t >> 6);   // slice id (SGPR)
    const int nqw  = NPTS / 64;
    const int b    = blockIdx.x / nqw;
    const int q0   = (blockIdx.x % nqw) * 64;
    const float* __restrict__ B = pb + (size_t)b * NPTS * 4;

    const int qi = q0 + lane;
    const float* qp = B + (size_t)(qi >> 1) * 8;
    const int e = qi & 1;
    const float qx = qp[0 + e], qy = qp[2 + e], qz = qp[4 + e], qw = qp[6 + e];
    const float qnp = qw + 1e-6f;               // keeps self-key positive
    const v2f qnp2 = {qnp, qnp};
    const v2f m2x2 = {-2.f * qx, -2.f * qx};
    const v2f m2y2 = {-2.f * qy, -2.f * qy};
    const v2f m2z2 = {-2.f * qz, -2.f * qz};
    unsigned vmask;
    asm("v_mov_b32 %0, 0xFFFFFFC0" : "=v"(vmask));   // keep 26 d2 bits in scan keys

    const float* __restrict__ Sp = B + (size_t)w * SLEN * 4;
    const unsigned jb = (unsigned)(w * SLEN);
    unsigned keyout[NWIN];

#pragma unroll
    for (int wi = 0; wi < NWIN; ++wi) {
        const float* __restrict__ Wp = Sp + wi * WLEN * 4;
        unsigned wmA = 0xFFFFFFFFu, wmB = 0xFFFFFFFFu;
#pragma unroll 32
        for (int j = 0; j < WLEN / 2; ++j) {
            const float4 ab = *reinterpret_cast<const float4*>(Wp + j * 8);
            const float4 cd = *reinterpret_cast<const float4*>(Wp + j * 8 + 4);
            const v2f xp = {ab.x, ab.y}, yp = {ab.z, ab.w};
            const v2f zp = {cd.x, cd.y}, wp = {cd.z, cd.w};
            v2f s2;
            asm("v_pk_add_f32 %0, %1, %2" : "=v"(s2) : "s"(wp), "v"(qnp2));
            asm("v_pk_fma_f32 %0, %1, %2, %0" : "+v"(s2) : "s"(zp), "v"(m2z2));
            asm("v_pk_fma_f32 %0, %1, %2, %0" : "+v"(s2) : "s"(yp), "v"(m2y2));
            asm("v_pk_fma_f32 %0, %1, %2, %0" : "+v"(s2) : "s"(xp), "v"(m2x2));
            unsigned k0, k1;
            asm("v_and_or_b32 %0, %1, %2, %3"
                : "=v"(k0) : "v"(__float_as_uint(s2.x)), "v"(vmask), "i"(2 * j));
            asm("v_and_or_b32 %0, %1, %2, %3"
                : "=v"(k1) : "v"(__float_as_uint(s2.y)), "v"(vmask), "i"(2 * j + 1));
            wmA = umin32(wmA, k0);
            wmB = umin32(wmB, k1);
        }
        const unsigned wm = umin32(wmA, wmB);
        const unsigned base = jb + (unsigned)(wi * WLEN);   // scalar per window
        keyout[wi] = (wm & 0xFFFFE000u) | base | (wm & 63u);
    }

#pragma unroll
    for (int wi = 0; wi < NWIN; ++wi) mrg[w][wi][lane] = keyout[wi];
    __syncthreads();

    // stage 1: waves 0..3 each merge 4 slices' window minima (self filtered)
    if (w < 4) {
        const unsigned selfidx = (unsigned)qi;
        unsigned best[KNN];
#pragma unroll
        for (int s = 0; s < KNN; ++s) best[s] = 0xFFFFFFFFu;
        for (int sl = 4 * w; sl < 4 * w + 4; ++sl) {
#pragma unroll
            for (int u = 0; u < KNN; ++u) {
                unsigned key = mrg[sl][u][lane];
                key = ((key & 0x1FFFu) == selfidx) ? 0xFFFFFFFFu : key;
                INSERT8(best, key);
            }
        }
#pragma unroll
        for (int s = 0; s < KNN; ++s) mrg[4 * w][s][lane] = best[s];
    }
    __syncthreads();

    // stage 2: wave 0 merges the 4 partials; closed-form deviation sum
    if (w == 0) {
        unsigned best[KNN];
#pragma unroll
        for (int s = 0; s < KNN; ++s) best[s] = 0xFFFFFFFFu;
        for (int g = 0; g < 4; ++g) {
#pragma unroll
            for (int u = 0; u < KNN; ++u) {
                const unsigned key = mrg[4 * g][u][lane];
                INSERT8(best, key);
            }
        }
        float sx = 0.f, sy = 0.f, sz = 0.f, sw = 0.f;
#pragma unroll
        for (int s = 0; s < KNN; ++s) {
            const unsigned n = best[s] & 0x1FFFu;
            const float* np = B + (size_t)(n >> 1) * 8 + (n & 1);
            sx += np[0]; sy += np[2]; sz += np[4]; sw += np[6];
        }
        float ssum = sw - (sx * sx + sy * sy + sz * sz) * (1.f / KNN);
#pragma unroll
        for (int o = 32; o > 0; o >>= 1) ssum += __shfl_down(ssum, o, 64);
        if (lane == 0) atomicAdd(&acc[2], (double)ssum);
    }
}

// Fused aux (512 thr): blocks [0,48) recon MSE (float4), [48,50) percep (float4),
// [50,114) boundary: 64 queries/block (one per lane), 8 waves x 256 c2-pairs via
// wave-uniform s_loads + packed-fp32 min of |p|^2-2p.q; |q|^2 added once.
__global__ __launch_bounds__(512) void aux_kernel(const float* __restrict__ a,
                                                  const float* __restrict__ bt,
                                                  const float* __restrict__ a2,
                                                  const float* __restrict__ b2,
                                                  const float* __restrict__ c1,
                                                  const float* __restrict__ c2p,
                                                  double* __restrict__ acc) {
    __shared__ float smem[8 * 64];
    const int t = threadIdx.x;
    const int blk = blockIdx.x;
    if (blk < 50) {
        float s;
        int which;
        if (blk < 48) {
            which = 0;
            const int i = blk * 512 + t;
            const float4 va = reinterpret_cast<const float4*>(a)[i];
            const float4 vb = reinterpret_cast<const float4*>(bt)[i];
            const float dx = va.x - vb.x, dy = va.y - vb.y;
            const float dz = va.z - vb.z, dw = va.w - vb.w;
            s = dx * dx + dy * dy + dz * dz + dw * dw;
        } else {
            which = 1;
            const int i = (blk - 48) * 512 + t;
            const float4 va = reinterpret_cast<const float4*>(a2)[i];
            const float4 vb = reinterpret_cast<const float4*>(b2)[i];
            const float dx = va.x - vb.x, dy = va.y - vb.y;
            const float dz = va.z - vb.z, dw = va.w - vb.w;
            s = dx * dx + dy * dy + dz * dz + dw * dw;
        }
#pragma unroll
        for (int o = 32; o > 0; o >>= 1) s += __shfl_down(s, o, 64);
        if ((t & 63) == 0) smem[t >> 6] = s;
        __syncthreads();
        if (t == 0) {
            float bs = 0.f;
#pragma unroll
            for (int i = 0; i < 8; ++i) bs += smem[i];
            atomicAdd(&acc[which], (double)bs);
        }
    } else {
        const int lane = t & 63;
        const int w8 = __builtin_amdgcn_readfirstlane(t >> 6);   // 0..7
        const int qi = (blk - 50) * 64 + lane;
        const float qx = c1[qi * 3 + 0];
        const float qy = c1[qi * 3 + 1];
        const float qz = c1[qi * 3 + 2];
        const float qn = qx * qx + qy * qy + qz * qz;
        const v2f zero2 = {0.f, 0.f};
        const v2f m2x2 = {-2.f * qx, -2.f * qx};
        const v2f m2y2 = {-2.f * qy, -2.f * qy};
        const v2f m2z2 = {-2.f * qz, -2.f * qz};
        float m = 3.0e38f;
        const float* __restrict__ Sp = c2p + (size_t)w8 * 256 * 8;   // 256 pairs
#pragma unroll 8
        for (int j = 0; j < 256; ++j) {
            const float4 ab = *reinterpret_cast<const float4*>(Sp + j * 8);
            const float4 cd = *reinterpret_cast<const float4*>(Sp + j * 8 + 4);
            const v2f xp = {ab.x, ab.y}, yp = {ab.z, ab.w};
            const v2f zp = {cd.x, cd.y}, wp = {cd.z, cd.w};
            v2f s2;
            asm("v_pk_add_f32 %0, %1, %2" : "=v"(s2) : "s"(wp), "v"(zero2));
            asm("v_pk_fma_f32 %0, %1, %2, %0" : "+v"(s2) : "s"(zp), "v"(m2z2));
            asm("v_pk_fma_f32 %0, %1, %2, %0" : "+v"(s2) : "s"(yp), "v"(m2y2));
            asm("v_pk_fma_f32 %0, %1, %2, %0" : "+v"(s2) : "s"(xp), "v"(m2x2));
            m = fminf(m, fminf(s2.x, s2.y));
        }
        smem[w8 * 64 + lane] = m;
        __syncthreads();
        if (w8 == 0) {
            float mm = smem[lane];
#pragma unroll
            for (int s = 1; s < 8; ++s) mm = fminf(mm, smem[s * 64 + lane]);
            const float d = sqrtf(fmaxf(mm + qn, 0.f));
            const bool in = d < 0.1f;
            float sc = in ? d : 0.f;
            float sn = in ? 1.f : 0.f;
#pragma unroll
            for (int o = 32; o > 0; o >>= 1) {
                sc += __shfl_down(sc, o, 64);
                sn += __shfl_down(sn, o, 64);
            }
            if (lane == 0) {
                atomicAdd(&acc[3], (double)sc);
                atomicAdd(&acc[4], (double)sn);
            }
        }
    }
}

__global__ void fin_kernel(const double* __restrict__ acc, float* __restrict__ out) {
    if (threadIdx.x == 0) {
        const double recon  = acc[0] / (double)(NBATCH * NPTS * 3);
        const double percep = acc[1] / 4096.0;
        const double cont   = acc[2] / (double)(NBATCH * NPTS * KNN);
        const double cnt    = acc[4];
        const double bnd    = (cnt > 0.0) ? acc[3] / ((cnt > 1.0) ? cnt : 1.0) : 0.0;
        const double total  = 1.0 * recon + 0.5 * percep + 0.5 * cont + 1.0 * bnd;
        out[0] = (float)recon;
        out[1] = (float)percep;
        out[2] = (float)cont;
        out[3] = (float)bnd;
        out[4] = (float)total;
    }
}

extern "C" void kernel_launch(void* const* d_in, const int* in_sizes, int n_in,
                              void* d_out, int out_size, void* d_ws, size_t ws_size,
                              hipStream_t stream) {
    const float* pred = (const float*)d_in[0];
    const float* targ = (const float*)d_in[1];
    const float* pf   = (const float*)d_in[2];
    const float* tf   = (const float*)d_in[3];
    const float* c1   = (const float*)d_in[4];
    const float* c2   = (const float*)d_in[5];
    float* out  = (float*)d_out;
    double* acc = (double*)d_ws;
    float* pb   = (float*)((char*)d_ws + PB_OFF);
    float* c2p  = (float*)((char*)d_ws + C2_OFF);

    hipLaunchKernelGGL(prep_kernel, dim3((NBATCH * NPTS / 2 + NCH / 2) / 256), dim3(256),
                       0, stream, pred, c2, pb, c2p, acc);
    hipLaunchKernelGGL(cont_kernel, dim3(NBATCH * (NPTS / 64)), dim3(1024), 0, stream,
                       pb, acc);
    hipLaunchKernelGGL(aux_kernel, dim3(114), dim3(512), 0, stream,
                       pred, targ, pf, tf, c1, c2p, acc);
    hipLaunchKernelGGL(fin_kernel, dim3(1), dim3(64), 0, stream, acc, out);
}